// Round 3
// baseline (2693.316 us; speedup 1.0000x reference)
//
#include <hip/hip_runtime.h>
#include <stdint.h>
#include <type_traits>

// LWTA MLP: L1 dense fp64-accum GEMM (+LWTA), L2 sparse fp64 (+LWTA), L3 sparse fp32.
// fp64 argmax decisions are REQUIRED: an LWTA flip vs the numpy(fp64) reference
// costs ~6e-3 output error vs threshold 4.28e-3. LWTA output is 1-of-16 sparse ->
// L2/L3 use compressed (value,index) A-operand: 16x fewer FLOPs.

#define BKT 32
#define TM 128          // block tile M
#define TN 128          // block tile N
#define ASTR (TM + 4)
#define BSTR (TN + 4)

// ---------------------------------------------------------------------------
// Dense fp64-accumulation GEMM, LWTA epilogue (layer 1).
// 256 threads, per-thread 8 rows x 8 cols (2 groups of 4 consecutive cols).
__global__ __launch_bounds__(256, 2)
void gemm_dense_f64_lwta(const float* __restrict__ A,
                         const float* __restrict__ Bw,
                         const float* __restrict__ bias,
                         int M, int N, int K,
                         double* __restrict__ vOut, uint8_t* __restrict__ iOut)
{
    __shared__ float As[BKT * ASTR];
    __shared__ float Bs[BKT * BSTR];

    const int t  = threadIdx.x;
    const int tx = t & 15;
    const int ty = t >> 4;
    const long m0 = (long)blockIdx.y * TM;
    const long n0 = (long)blockIdx.x * TN;

    double acc[8][2][4];
#pragma unroll
    for (int r = 0; r < 8; ++r)
#pragma unroll
        for (int g = 0; g < 2; ++g)
#pragma unroll
            for (int d = 0; d < 4; ++d) acc[r][g][d] = 0.0;

    const int nkt = K / BKT;
    for (int kt = 0; kt < nkt; ++kt) {
        const int k0 = kt * BKT;
        __syncthreads();
        // stage B: Bs[k][j] = Bw[n0+j][k0+k]; 128 cols x 8 quads = 1024 slots -> 4 iters
#pragma unroll
        for (int i = 0; i < 4; ++i) {
            const int f   = i * 256 + t;
            const int col = f >> 3;
            const int kq  = (f & 7) * 4;
            const float4 w = *reinterpret_cast<const float4*>(
                &Bw[(n0 + col) * (long)K + k0 + kq]);
            Bs[(kq + 0) * BSTR + col] = w.x;
            Bs[(kq + 1) * BSTR + col] = w.y;
            Bs[(kq + 2) * BSTR + col] = w.z;
            Bs[(kq + 3) * BSTR + col] = w.w;
        }
        // stage A: As[k][row]; 128 rows x 8 quads = 1024 slots -> 4 iters
#pragma unroll
        for (int i = 0; i < 4; ++i) {
            const int f   = i * 256 + t;
            const int row = f >> 3;
            const int kq  = (f & 7) * 4;
            const float4 a = *reinterpret_cast<const float4*>(
                &A[(m0 + row) * (long)K + k0 + kq]);
            As[(kq + 0) * ASTR + row] = a.x;
            As[(kq + 1) * ASTR + row] = a.y;
            As[(kq + 2) * ASTR + row] = a.z;
            As[(kq + 3) * ASTR + row] = a.w;
        }
        __syncthreads();

#pragma unroll
        for (int kk = 0; kk < BKT; ++kk) {
            const float4 a0 = *reinterpret_cast<const float4*>(&As[kk * ASTR + ty * 8]);
            const float4 a1 = *reinterpret_cast<const float4*>(&As[kk * ASTR + ty * 8 + 4]);
            const float4 b0 = *reinterpret_cast<const float4*>(&Bs[kk * BSTR + tx * 4]);
            const float4 b1 = *reinterpret_cast<const float4*>(&Bs[kk * BSTR + 64 + tx * 4]);
            const double ad[8] = {(double)a0.x, (double)a0.y, (double)a0.z, (double)a0.w,
                                  (double)a1.x, (double)a1.y, (double)a1.z, (double)a1.w};
            const double bd[2][4] = {{(double)b0.x, (double)b0.y, (double)b0.z, (double)b0.w},
                                     {(double)b1.x, (double)b1.y, (double)b1.z, (double)b1.w}};
#pragma unroll
            for (int r = 0; r < 8; ++r)
#pragma unroll
                for (int g = 0; g < 2; ++g)
#pragma unroll
                    for (int d = 0; d < 4; ++d)
                        acc[r][g][d] += ad[r] * bd[g][d];
        }
    }

    // LWTA epilogue (double), blocks of 16 = one 4-lane quad
    const int nb = N >> 4;
#pragma unroll
    for (int r = 0; r < 8; ++r) {
        const long row = m0 + ty * 8 + r;
#pragma unroll
        for (int g = 0; g < 2; ++g) {
            double bv = -2.0;
            int    bi = 0;
#pragma unroll
            for (int d = 0; d < 4; ++d) {
                const long j = n0 + g * 64 + tx * 4 + d;
                double x = acc[r][g][d] + (double)bias[j];
                x = fmin(fmax(x, -1.0), 1.0);
                const int li = (tx & 3) * 4 + d;
                if (x > bv) { bv = x; bi = li; }
            }
#pragma unroll
            for (int mk = 1; mk <= 2; mk <<= 1) {
                const double ov = __shfl_xor(bv, mk);
                const int    oi = __shfl_xor(bi, mk);
                if (ov > bv || (ov == bv && oi < bi)) { bv = ov; bi = oi; }
            }
            if ((tx & 3) == 0) {
                const long blk = (n0 >> 4) + g * 4 + (tx >> 2);
                vOut[row * nb + blk] = bv;
                iOut[row * nb + blk] = (uint8_t)bi;
            }
        }
    }
}

// ---------------------------------------------------------------------------
// Sparse-A GEMM: A is compressed LWTA output (one value+index per 16-block).
// F64: fp64 accumulate + LWTA epilogue (layer 2, vA double).
// !F64: fp32 accumulate + dense output (layer 3, vA float).
template<bool F64>
__global__ __launch_bounds__(256, 2)
void gemm_sparse(const void* __restrict__ vA_, const uint8_t* __restrict__ iA,
                 const float* __restrict__ Bw, const float* __restrict__ bias,
                 int M, int N, int K,
                 float* __restrict__ vOut, uint8_t* __restrict__ iOut,
                 float* __restrict__ dOut)
{
    typedef typename std::conditional<F64, double, float>::type AccT;
    const AccT* __restrict__ vA = (const AccT*)vA_;

    __shared__ float Bs[BKT * BSTR];
    __shared__ AccT  Av[2 * TM];
    __shared__ int   Ai[2 * TM];

    const int t  = threadIdx.x;
    const int tx = t & 15;
    const int ty = t >> 4;
    const long m0 = (long)blockIdx.y * TM;
    const long n0 = (long)blockIdx.x * TN;
    const int nbK = K >> 4;

    AccT acc[8][2][4];
#pragma unroll
    for (int r = 0; r < 8; ++r)
#pragma unroll
        for (int g = 0; g < 2; ++g)
#pragma unroll
            for (int d = 0; d < 4; ++d) acc[r][g][d] = (AccT)0;

    const int nkt = K / BKT;
    for (int kt = 0; kt < nkt; ++kt) {
        const int k0 = kt * BKT;
        __syncthreads();
        // stage B: Bs[k][j] = Bw[n0+j][k0+k]; 1024 slots -> 4 iters
#pragma unroll
        for (int i = 0; i < 4; ++i) {
            const int f   = i * 256 + t;
            const int col = f >> 3;
            const int kq  = (f & 7) * 4;
            const float4 w = *reinterpret_cast<const float4*>(
                &Bw[(n0 + col) * (long)K + k0 + kq]);
            Bs[(kq + 0) * BSTR + col] = w.x;
            Bs[(kq + 1) * BSTR + col] = w.y;
            Bs[(kq + 2) * BSTR + col] = w.z;
            Bs[(kq + 3) * BSTR + col] = w.w;
        }
        // stage compressed A: 2 k-blocks x 128 rows
        {
            const int row  = t & 127;
            const int half = t >> 7;
            const long c = (m0 + row) * (long)nbK + (k0 >> 4) + half;
            Av[half * TM + row] = vA[c];
            Ai[half * TM + row] = (int)iA[c];
        }
        __syncthreads();

        // sparse inner: one nonzero per (row, 16-block) -> 2 gathers, 16 FMAs / row
#pragma unroll
        for (int r = 0; r < 8; ++r) {
            const int row = ty * 8 + r;
#pragma unroll
            for (int kb = 0; kb < 2; ++kb) {
                const AccT v  = Av[kb * TM + row];
                const int  kw = kb * 16 + Ai[kb * TM + row];
                const float4 b0 = *reinterpret_cast<const float4*>(&Bs[kw * BSTR + tx * 4]);
                const float4 b1 = *reinterpret_cast<const float4*>(&Bs[kw * BSTR + 64 + tx * 4]);
                acc[r][0][0] += v * (AccT)b0.x;
                acc[r][0][1] += v * (AccT)b0.y;
                acc[r][0][2] += v * (AccT)b0.z;
                acc[r][0][3] += v * (AccT)b0.w;
                acc[r][1][0] += v * (AccT)b1.x;
                acc[r][1][1] += v * (AccT)b1.y;
                acc[r][1][2] += v * (AccT)b1.z;
                acc[r][1][3] += v * (AccT)b1.w;
            }
        }
    }

    if (F64) {
        // LWTA epilogue -> compressed fp32 output
        const int nb = N >> 4;
#pragma unroll
        for (int r = 0; r < 8; ++r) {
            const long row = m0 + ty * 8 + r;
#pragma unroll
            for (int g = 0; g < 2; ++g) {
                AccT bv = (AccT)(-2.0);
                int  bi = 0;
#pragma unroll
                for (int d = 0; d < 4; ++d) {
                    const long j = n0 + g * 64 + tx * 4 + d;
                    AccT x = acc[r][g][d] + (AccT)bias[j];
                    x = fmin(fmax(x, (AccT)-1.0), (AccT)1.0);
                    const int li = (tx & 3) * 4 + d;
                    if (x > bv) { bv = x; bi = li; }
                }
#pragma unroll
                for (int mk = 1; mk <= 2; mk <<= 1) {
                    const AccT ov = __shfl_xor(bv, mk);
                    const int  oi = __shfl_xor(bi, mk);
                    if (ov > bv || (ov == bv && oi < bi)) { bv = ov; bi = oi; }
                }
                if ((tx & 3) == 0) {
                    const long blk = (n0 >> 4) + g * 4 + (tx >> 2);
                    vOut[row * nb + blk] = (float)bv;
                    iOut[row * nb + blk] = (uint8_t)bi;
                }
            }
        }
    } else {
        // dense epilogue -> d_out
#pragma unroll
        for (int r = 0; r < 8; ++r) {
            const long row = m0 + ty * 8 + r;
#pragma unroll
            for (int g = 0; g < 2; ++g) {
                const long j = n0 + g * 64 + tx * 4;
                float4 o;
                o.x = (float)(acc[r][g][0] + (AccT)bias[j + 0]);
                o.y = (float)(acc[r][g][1] + (AccT)bias[j + 1]);
                o.z = (float)(acc[r][g][2] + (AccT)bias[j + 2]);
                o.w = (float)(acc[r][g][3] + (AccT)bias[j + 3]);
                *reinterpret_cast<float4*>(&dOut[row * (long)N + j]) = o;
            }
        }
    }
}

extern "C" void kernel_launch(void* const* d_in, const int* in_sizes, int n_in,
                              void* d_out, int out_size, void* d_ws, size_t ws_size,
                              hipStream_t stream)
{
    const float* x    = (const float*)d_in[0];
    const float* W1   = (const float*)d_in[1];
    const float* b1   = (const float*)d_in[2];
    const float* W2   = (const float*)d_in[3];
    const float* b2   = (const float*)d_in[4];
    const float* Wout = (const float*)d_in[5];
    const float* bout = (const float*)d_in[6];
    float* out = (float*)d_out;
    (void)in_sizes; (void)n_in; (void)out_size; (void)ws_size;

    const int B = 8192, Din = 1024, H = 4096, Dout = 1024;

    // workspace: v1 double 16MB | i1 2MB | v2 float 8MB | i2 2MB  (28MB total)
    double*  v1 = (double*)d_ws;
    uint8_t* i1 = (uint8_t*)((char*)d_ws + (16ll << 20));
    float*   v2 = (float*)((char*)d_ws + (18ll << 20));
    uint8_t* i2 = (uint8_t*)((char*)d_ws + (26ll << 20));

    dim3 blk(256);

    // L1: h1 = LWTA(clip(x @ W1^T + b1))  dense fp64
    dim3 g1(H / TN, B / TM);
    gemm_dense_f64_lwta<<<g1, blk, 0, stream>>>(x, W1, b1, B, H, Din, v1, i1);

    // L2: h2 = LWTA(clip(h1 @ W2^T + b2)) sparse fp64
    dim3 g2(H / TN, B / TM);
    gemm_sparse<true><<<g2, blk, 0, stream>>>(v1, i1, W2, b2, B, H, H, v2, i2, nullptr);

    // L3: out = h2 @ Wout^T + bout        sparse fp32
    dim3 g3(Dout / TN, B / TM);
    gemm_sparse<false><<<g3, blk, 0, stream>>>(v2, i2, Wout, bout, B, Dout, H,
                                               nullptr, nullptr, out);
}